// Round 1
// baseline (307.808 us; speedup 1.0000x reference)
//
#include <hip/hip_runtime.h>

// Problem constants (from reference): B=128, C_IN=128, C_HID=256, C_OUT=128,
// H*W=1600, NUM_EXPERTS=8, TOP_K=2.
#define BATCH 128
#define CIN   128
#define CHID  256
#define COUT  128
#define HWPX  1600
#define PXT   64          // pixels per block tile
#define NPXT  25          // 1600 / 64

typedef __attribute__((ext_vector_type(8))) short bf16x8;  // 8 bf16 = 4 VGPRs
typedef __attribute__((ext_vector_type(4))) float f32x4;   // MFMA C/D

__device__ __forceinline__ unsigned short f2bf(float f) {
  // round-to-nearest-even fp32 -> bf16
  unsigned int u = __builtin_bit_cast(unsigned int, f);
  u += 0x7FFFu + ((u >> 16) & 1u);
  return (unsigned short)(u >> 16);
}

__device__ __forceinline__ float silu_f(float v) {
  return v / (1.0f + __expf(-v));
}

__global__ __launch_bounds__(256) void convert_w_kernel(
    const float* __restrict__ W1, const float* __restrict__ W2,
    unsigned short* __restrict__ W1b, unsigned short* __restrict__ W2b) {
  int i = blockIdx.x * 256 + threadIdx.x;  // 262144 threads, covers 8*256*128
  W1b[i] = f2bf(W1[i]);
  W2b[i] = f2bf(W2[i]);
}

__global__ __launch_bounds__(256) void moe_kernel(
    const float* __restrict__ x, const float* __restrict__ wts,
    const int* __restrict__ idx, const unsigned short* __restrict__ W1,
    const float* __restrict__ b1, const unsigned short* __restrict__ W2,
    const float* __restrict__ b2, float* __restrict__ out) {
  // xs: x tile, bf16, [px][cin], +8 pad keeps rows 16B-aligned for ds_read_b128
  __shared__ unsigned short xs[PXT][CIN + 8];
  // hs: half of hidden activations, bf16, [px][ch_within_half]
  __shared__ unsigned short hs[PXT][128 + 8];

  const int tid  = threadIdx.x;
  const int wave = tid >> 6;
  const int lane = tid & 63;
  const int q    = lane >> 4;   // quad 0..3
  const int r16  = lane & 15;   // 0..15

  const int blk = blockIdx.x;
  const int b   = blk / NPXT;
  const int pt  = blk - b * NPXT;
  const int px0 = pt * PXT;

  // ---- stage x tile -> xs (fp32 global, coalesced float4, -> bf16 transposed)
  {
    const float* xb = x + (long)b * CIN * HWPX + px0;
    const int prow = tid >> 4;        // 0..15 : cin sub-row
    const int ppx  = (tid & 15) * 4;  // 0..60 : 4 px per thread
#pragma unroll
    for (int it = 0; it < 8; ++it) {
      const int cin = it * 16 + prow;
      const float4 v = *reinterpret_cast<const float4*>(xb + (long)cin * HWPX + ppx);
      xs[ppx + 0][cin] = f2bf(v.x);
      xs[ppx + 1][cin] = f2bf(v.y);
      xs[ppx + 2][cin] = f2bf(v.z);
      xs[ppx + 3][cin] = f2bf(v.w);
    }
  }
  __syncthreads();

  f32x4 accO[2][4];
#pragma unroll
  for (int mt = 0; mt < 2; ++mt)
#pragma unroll
    for (int nt = 0; nt < 4; ++nt) accO[mt][nt] = (f32x4){0.f, 0.f, 0.f, 0.f};

  for (int slot = 0; slot < 2; ++slot) {
    const int   e = idx[b * 2 + slot];
    const float g = wts[b * 2 + slot];
    const unsigned short* W1e = W1 + (long)e * CHID * CIN;
    const unsigned short* W2e = W2 + (long)e * COUT * CHID;
    const float* b1e = b1 + e * CHID;

    f32x4 acc2[2][4];
#pragma unroll
    for (int mt = 0; mt < 2; ++mt)
#pragma unroll
      for (int nt = 0; nt < 4; ++nt) acc2[mt][nt] = (f32x4){0.f, 0.f, 0.f, 0.f};

#pragma unroll
    for (int half = 0; half < 2; ++half) {
      // ---- GEMM1 (this half): h[ch][px] = W1[ch][cin] * x[cin][px]
      f32x4 acc1[2][4];
#pragma unroll
      for (int mt = 0; mt < 2; ++mt)
#pragma unroll
        for (int nt = 0; nt < 4; ++nt) acc1[mt][nt] = (f32x4){0.f, 0.f, 0.f, 0.f};

#pragma unroll
      for (int ks = 0; ks < 4; ++ks) {
        const int kofs = ks * 32 + q * 8;
        const int row0 = half * 128 + wave * 32 + r16;
        const bf16x8 a0 = *reinterpret_cast<const bf16x8*>(W1e + (row0) * CIN + kofs);
        const bf16x8 a1 = *reinterpret_cast<const bf16x8*>(W1e + (row0 + 16) * CIN + kofs);
        bf16x8 bb[4];
#pragma unroll
        for (int nt = 0; nt < 4; ++nt)
          bb[nt] = *reinterpret_cast<const bf16x8*>(&xs[nt * 16 + r16][kofs]);
#pragma unroll
        for (int nt = 0; nt < 4; ++nt) {
          acc1[0][nt] = __builtin_amdgcn_mfma_f32_16x16x32_bf16(a0, bb[nt], acc1[0][nt], 0, 0, 0);
          acc1[1][nt] = __builtin_amdgcn_mfma_f32_16x16x32_bf16(a1, bb[nt], acc1[1][nt], 0, 0, 0);
        }
      }

      // ---- bias + SiLU -> hs (bf16), 4 consecutive ch per lane (D-row = q*4+r)
#pragma unroll
      for (int mt = 0; mt < 2; ++mt) {
        const int chh = wave * 32 + mt * 16 + q * 4;  // ch within half
        const f32x4 bias = *reinterpret_cast<const f32x4*>(b1e + half * 128 + chh);
#pragma unroll
        for (int nt = 0; nt < 4; ++nt) {
          const f32x4 v = acc1[mt][nt] + bias;
          const unsigned int lo = (unsigned int)f2bf(silu_f(v[0])) |
                                  ((unsigned int)f2bf(silu_f(v[1])) << 16);
          const unsigned int hi = (unsigned int)f2bf(silu_f(v[2])) |
                                  ((unsigned int)f2bf(silu_f(v[3])) << 16);
          *reinterpret_cast<uint2*>(&hs[nt * 16 + r16][chh]) = make_uint2(lo, hi);
        }
      }
      __syncthreads();  // hs fully written

      // ---- GEMM2 partial-K over this half: y[co][px] += W2[co][ch] * h[ch][px]
#pragma unroll
      for (int ks = 0; ks < 4; ++ks) {
        const int kofs = ks * 32 + q * 8;  // within half
        const int row0 = wave * 32 + r16;
        const bf16x8 a0 = *reinterpret_cast<const bf16x8*>(W2e + (row0) * CHID + half * 128 + kofs);
        const bf16x8 a1 = *reinterpret_cast<const bf16x8*>(W2e + (row0 + 16) * CHID + half * 128 + kofs);
        bf16x8 bb[4];
#pragma unroll
        for (int nt = 0; nt < 4; ++nt)
          bb[nt] = *reinterpret_cast<const bf16x8*>(&hs[nt * 16 + r16][kofs]);
#pragma unroll
        for (int nt = 0; nt < 4; ++nt) {
          acc2[0][nt] = __builtin_amdgcn_mfma_f32_16x16x32_bf16(a0, bb[nt], acc2[0][nt], 0, 0, 0);
          acc2[1][nt] = __builtin_amdgcn_mfma_f32_16x16x32_bf16(a1, bb[nt], acc2[1][nt], 0, 0, 0);
        }
      }
      __syncthreads();  // hs consumed, safe to overwrite next half/slot
    }

    // ---- gated accumulate: accO += g * (acc2 + b2)
    const float* b2e = b2 + e * COUT;
#pragma unroll
    for (int mt = 0; mt < 2; ++mt) {
      const f32x4 bias2 = *reinterpret_cast<const f32x4*>(b2e + wave * 32 + mt * 16 + q * 4);
#pragma unroll
      for (int nt = 0; nt < 4; ++nt) accO[mt][nt] += g * (acc2[mt][nt] + bias2);
    }
  }

  // ---- store out[b][co][px0+px], each lane owns 4 consecutive co x 16 px
  const long ob = (long)b * COUT * HWPX + px0;
#pragma unroll
  for (int mt = 0; mt < 2; ++mt) {
    const int co = wave * 32 + mt * 16 + q * 4;
#pragma unroll
    for (int nt = 0; nt < 4; ++nt) {
      const int px = nt * 16 + r16;
#pragma unroll
      for (int r = 0; r < 4; ++r)
        out[ob + (long)(co + r) * HWPX + px] = accO[mt][nt][r];
    }
  }
}

extern "C" void kernel_launch(void* const* d_in, const int* in_sizes, int n_in,
                              void* d_out, int out_size, void* d_ws, size_t ws_size,
                              hipStream_t stream) {
  const float* x   = (const float*)d_in[0];
  const float* wts = (const float*)d_in[1];
  const int*   idx = (const int*)d_in[2];
  const float* W1  = (const float*)d_in[3];
  const float* b1  = (const float*)d_in[4];
  const float* W2  = (const float*)d_in[5];
  const float* b2  = (const float*)d_in[6];
  float* out = (float*)d_out;

  unsigned short* W1b = (unsigned short*)d_ws;                       // 8*256*128
  unsigned short* W2b = (unsigned short*)d_ws + (8 * CHID * CIN);    // 8*128*256

  // 8*256*128 = 262144 elements each
  convert_w_kernel<<<262144 / 256, 256, 0, stream>>>(W1, W2, W1b, W2b);

  moe_kernel<<<BATCH * NPXT, 256, 0, stream>>>(x, wts, idx, W1b, b1, W2b, b2, out);
}